// Round 6
// baseline (88.479 us; speedup 1.0000x reference)
//
#include <hip/hip_runtime.h>
#include <hip/hip_bf16.h>

#define N_NODES 65536
#define NUM_G   64
#define GSIZE   1024
#define DIM     64

using frag_ab = __attribute__((ext_vector_type(8))) short;   // 8 bf16 (4 VGPRs)
using f32x4   = __attribute__((ext_vector_type(4))) float;   // 4 fp32 accum

__device__ __forceinline__ unsigned short f2bf(float x) {
    union { float f; unsigned int u; } v; v.f = x;
    unsigned int r = v.u + 0x7FFFu + ((v.u >> 16) & 1u);   // RNE
    return (unsigned short)(r >> 16);
}

// Kernel 1: fp32 row-normalize z1,z2 -> bf16 copies; pos = (z1n . z2n) * inv_t (fp32).
__global__ __launch_bounds__(256) void normalize_k(
    const float* __restrict__ z1, const float* __restrict__ z2,
    unsigned short* __restrict__ z1n, unsigned short* __restrict__ z2n,
    float* __restrict__ pos)
{
    int tid = threadIdx.x;
    int row = blockIdx.x * 16 + (tid >> 4);
    int l4  = tid & 15;
    float4 v1 = *((const float4*)(z1 + (size_t)row * DIM) + l4);
    float4 v2 = *((const float4*)(z2 + (size_t)row * DIM) + l4);
    float ss1 = v1.x*v1.x + v1.y*v1.y + v1.z*v1.z + v1.w*v1.w;
    float ss2 = v2.x*v2.x + v2.y*v2.y + v2.z*v2.z + v2.w*v2.w;
    float dt  = v1.x*v2.x + v1.y*v2.y + v1.z*v2.z + v1.w*v2.w;
    #pragma unroll
    for (int m = 1; m < 16; m <<= 1) {
        ss1 += __shfl_xor(ss1, m);
        ss2 += __shfl_xor(ss2, m);
        dt  += __shfl_xor(dt,  m);
    }
    float in1 = 1.0f / sqrtf(ss1);
    float in2 = 1.0f / sqrtf(ss2);
    ushort4 o1, o2;
    o1.x = f2bf(v1.x*in1); o1.y = f2bf(v1.y*in1); o1.z = f2bf(v1.z*in1); o1.w = f2bf(v1.w*in1);
    o2.x = f2bf(v2.x*in2); o2.y = f2bf(v2.y*in2); o2.z = f2bf(v2.z*in2); o2.w = f2bf(v2.w*in2);
    *((ushort4*)(z1n + (size_t)row * DIM) + l4) = o1;
    *((ushort4*)(z2n + (size_t)row * DIM) + l4) = o2;
    if (l4 == 0) pos[row] = dt * in1 * in2 * 2.0f;   // inv_t = 2
}

// Kernel 2: no LDS staging, no main-loop barriers. 1024 blocks = 64 graphs x 16
// stripes of 64 rows; 4 waves/SIMD. Per wave: A = 64 rows in regs (32 VGPR),
// streams 512 of the 2048 virtual cols [z2 | z1] from L2 (graph L2-resident via
// XCD clustering). PHASE-SPLIT per 16-col tile: all 8 MFMAs back-to-back into
// c[0..3], THEN the exp phase -- c[0] has retired long before its first read,
// so no MFMA->VALU latency chain. 2-tile rotating register prefetch.
__global__ __launch_bounds__(256, 4) void grace_main_k(
    const unsigned short* __restrict__ z1n,
    const unsigned short* __restrict__ z2n,
    const float* __restrict__ pos,
    float* __restrict__ partials)
{
    __shared__ float sums[4][64];   // per-wave partial row sums
    __shared__ float red[4];

    int tid = threadIdx.x;
    int n = blockIdx.x;
    int g = (n & 7) + 8 * (n >> 7);   // all 16 blocks of a graph share XCD (n%8 model)
    int stripe = (n >> 3) & 15;
    int w = tid >> 6, l = tid & 63;
    const unsigned short* z1g = z1n + (size_t)g * GSIZE * DIM;
    const unsigned short* z2g = z2n + (size_t)g * GSIZE * DIM;
    int rowBase = stripe * 64;

    // A fragments: 64 rows, 4 tiles x 2 K-halves. row = rowBase + rt*16 + (l&15)
    int ar = l & 15, ak = (l >> 4) * 8;
    frag_ab A[4][2];
    #pragma unroll
    for (int rt = 0; rt < 4; ++rt) {
        const unsigned short* p = z1g + (rowBase + rt * 16 + ar) * DIM + ak;
        A[rt][0] = *(const frag_ab*)(p);
        A[rt][1] = *(const frag_ab*)(p + 32);
    }

    float expacc[4][4] = {};   // static indexing only

    // Column stream: wave w covers virtual cols [w*512, w*512+512) of [z2 | z1].
    const unsigned short* sb =
        ((w < 2) ? z2g : z1g) + (((w & 1) * 512 + ar) * DIM + ak);

    const float K1 = 2.8853900817779268f;   // 2 * log2(e)   (inv_t=2 folded)
    const float K0 = -2.8853900817779268f;  // -2 * log2(e)  (fixed shift m=2)

    auto compute = [&](frag_ab b0, frag_ab b1) {
        f32x4 z = {0.f, 0.f, 0.f, 0.f};
        // phase 1: all MFMAs, no VALU interleaved by data deps
        f32x4 c0 = __builtin_amdgcn_mfma_f32_16x16x32_bf16(A[0][0], b0, z, 0, 0, 0);
        f32x4 c1 = __builtin_amdgcn_mfma_f32_16x16x32_bf16(A[1][0], b0, z, 0, 0, 0);
        f32x4 c2 = __builtin_amdgcn_mfma_f32_16x16x32_bf16(A[2][0], b0, z, 0, 0, 0);
        f32x4 c3 = __builtin_amdgcn_mfma_f32_16x16x32_bf16(A[3][0], b0, z, 0, 0, 0);
        c0 = __builtin_amdgcn_mfma_f32_16x16x32_bf16(A[0][1], b1, c0, 0, 0, 0);
        c1 = __builtin_amdgcn_mfma_f32_16x16x32_bf16(A[1][1], b1, c1, 0, 0, 0);
        c2 = __builtin_amdgcn_mfma_f32_16x16x32_bf16(A[2][1], b1, c2, 0, 0, 0);
        c3 = __builtin_amdgcn_mfma_f32_16x16x32_bf16(A[3][1], b1, c3, 0, 0, 0);
        // phase 2: exp/accumulate (c0 retired ~8 MFMA-issues ago)
        #pragma unroll
        for (int r = 0; r < 4; ++r) {
            expacc[0][r] += __builtin_amdgcn_exp2f(fmaf(c0[r], K1, K0));
            expacc[1][r] += __builtin_amdgcn_exp2f(fmaf(c1[r], K1, K0));
            expacc[2][r] += __builtin_amdgcn_exp2f(fmaf(c2[r], K1, K0));
            expacc[3][r] += __builtin_amdgcn_exp2f(fmaf(c3[r], K1, K0));
        }
    };

    frag_ab bA0 = *(const frag_ab*)(sb);
    frag_ab bA1 = *(const frag_ab*)(sb + 32);

    #pragma unroll 1
    for (int t = 0; t < 32; t += 2) {
        frag_ab bB0 = *(const frag_ab*)(sb + 16 * DIM);        // tile t+1
        frag_ab bB1 = *(const frag_ab*)(sb + 16 * DIM + 32);
        compute(bA0, bA1);                                     // tile t
        if (t < 30) {
            bA0 = *(const frag_ab*)(sb + 32 * DIM);            // tile t+2
            bA1 = *(const frag_ab*)(sb + 32 * DIM + 32);
        }
        compute(bB0, bB1);                                     // tile t+1
        sb += 32 * DIM;
    }

    // Reduce C cols (low-4 lane bits); C/D layout: row = (l>>4)*4 + r, col = l&15.
    #pragma unroll
    for (int rt = 0; rt < 4; ++rt) {
        #pragma unroll
        for (int r = 0; r < 4; ++r) {
            float s = expacc[rt][r];
            s += __shfl_xor(s, 1); s += __shfl_xor(s, 2);
            s += __shfl_xor(s, 4); s += __shfl_xor(s, 8);
            if ((l & 15) == 0) sums[w][rt * 16 + (l >> 4) * 4 + r] = s;
        }
    }
    __syncthreads();

    float term = 0.f;
    if (tid < 64) {
        float S = sums[0][tid] + sums[1][tid] + sums[2][tid] + sums[3][tid];
        // shift m=2; sim11 diag contributes exp(0)=1, excluded in closed form
        term = 2.0f + __logf(S - 1.0f) - pos[g * GSIZE + rowBase + tid];
    }
    #pragma unroll
    for (int m = 1; m < 64; m <<= 1) term += __shfl_xor(term, m);
    if (l == 0) red[w] = term;   // waves 1..3 contribute 0
    __syncthreads();
    if (tid == 0) partials[n] = red[0] + red[1] + red[2] + red[3];
}

// Kernel 3: deterministic 1024 -> 1 reduce, mean over nodes.
__global__ __launch_bounds__(256) void final_reduce_k(
    const float* __restrict__ partials, float* __restrict__ out)
{
    int tid = threadIdx.x;
    float s = partials[tid] + partials[tid + 256] + partials[tid + 512] + partials[tid + 768];
    #pragma unroll
    for (int m = 1; m < 64; m <<= 1) s += __shfl_xor(s, m);
    __shared__ float red[4];
    if ((tid & 63) == 0) red[tid >> 6] = s;
    __syncthreads();
    if (tid == 0) out[0] = (red[0] + red[1] + red[2] + red[3]) * (1.0f / N_NODES);
}

extern "C" void kernel_launch(void* const* d_in, const int* in_sizes, int n_in,
                              void* d_out, int out_size, void* d_ws, size_t ws_size,
                              hipStream_t stream)
{
    const float* z1 = (const float*)d_in[0];
    const float* z2 = (const float*)d_in[1];
    char* ws = (char*)d_ws;
    unsigned short* z1n = (unsigned short*)ws;                       // 8 MB
    unsigned short* z2n = (unsigned short*)(ws + 8388608);           // 8 MB
    float* pos          = (float*)(ws + 16777216);                   // 256 KB
    float* partials     = (float*)(ws + 17039360);                   // 4 KB

    normalize_k<<<dim3(N_NODES / 16), dim3(256), 0, stream>>>(z1, z2, z1n, z2n, pos);
    // Launched twice deliberately this round: idempotent (rewrites identical
    // partials), and the 2nd warm dispatch lifts grace_main_k into the rocprof
    // top-5 (above the 40us fillBuffer rows) so we finally get its counters.
    grace_main_k<<<dim3(NUM_G * 16), dim3(256), 0, stream>>>(z1n, z2n, pos, partials);
    grace_main_k<<<dim3(NUM_G * 16), dim3(256), 0, stream>>>(z1n, z2n, pos, partials);
    final_reduce_k<<<dim3(1), dim3(256), 0, stream>>>(partials, (float*)d_out);
}

// Round 7
// 58.896 us; speedup vs baseline: 1.5023x; 1.5023x over previous
//
#include <hip/hip_runtime.h>
#include <hip/hip_bf16.h>

#define N_NODES 65536
#define NUM_G   64
#define GSIZE   1024
#define DIM     64

using frag_ab = __attribute__((ext_vector_type(8))) short;   // 8 bf16 (4 VGPRs)
using f32x4   = __attribute__((ext_vector_type(4))) float;   // 4 fp32 accum

__device__ __forceinline__ unsigned short f2bf(float x) {
    union { float f; unsigned int u; } v; v.f = x;
    unsigned int r = v.u + 0x7FFFu + ((v.u >> 16) & 1u);   // RNE
    return (unsigned short)(r >> 16);
}

// Kernel 1: fp32 row-normalize z1,z2 -> bf16 copies; pos = (z1n . z2n) * inv_t (fp32).
__global__ __launch_bounds__(256) void normalize_k(
    const float* __restrict__ z1, const float* __restrict__ z2,
    unsigned short* __restrict__ z1n, unsigned short* __restrict__ z2n,
    float* __restrict__ pos)
{
    int tid = threadIdx.x;
    int row = blockIdx.x * 16 + (tid >> 4);
    int l4  = tid & 15;
    float4 v1 = *((const float4*)(z1 + (size_t)row * DIM) + l4);
    float4 v2 = *((const float4*)(z2 + (size_t)row * DIM) + l4);
    float ss1 = v1.x*v1.x + v1.y*v1.y + v1.z*v1.z + v1.w*v1.w;
    float ss2 = v2.x*v2.x + v2.y*v2.y + v2.z*v2.z + v2.w*v2.w;
    float dt  = v1.x*v2.x + v1.y*v2.y + v1.z*v2.z + v1.w*v2.w;
    #pragma unroll
    for (int m = 1; m < 16; m <<= 1) {
        ss1 += __shfl_xor(ss1, m);
        ss2 += __shfl_xor(ss2, m);
        dt  += __shfl_xor(dt,  m);
    }
    float in1 = 1.0f / sqrtf(ss1);
    float in2 = 1.0f / sqrtf(ss2);
    ushort4 o1, o2;
    o1.x = f2bf(v1.x*in1); o1.y = f2bf(v1.y*in1); o1.z = f2bf(v1.z*in1); o1.w = f2bf(v1.w*in1);
    o2.x = f2bf(v2.x*in2); o2.y = f2bf(v2.y*in2); o2.z = f2bf(v2.z*in2); o2.w = f2bf(v2.w*in2);
    *((ushort4*)(z1n + (size_t)row * DIM) + l4) = o1;
    *((ushort4*)(z2n + (size_t)row * DIM) + l4) = o2;
    if (l4 == 0) pos[row] = dt * in1 * in2 * 2.0f;   // inv_t = 2
}

// Kernel 2: no LDS staging, no main-loop barriers. 1024 blocks = 64 graphs x 16
// stripes of 64 rows. Per wave: A = 64 rows in regs, streams 512 of the 2048
// virtual cols [z2 | z1] from L2/L3. 4-DEEP named register prefetch (p0..p3):
// loads for tile t+4 issue right after tile t is consumed -> ~3-compute
// load->use distance (~1900 wall cyc at ~3 waves/SIMD) covers L2/L3 latency,
// which R6 counters showed as the ~55% all-wave stall (VALU 32 + MFMA 14 busy).
__global__ __launch_bounds__(256, 4) void grace_main_k(
    const unsigned short* __restrict__ z1n,
    const unsigned short* __restrict__ z2n,
    const float* __restrict__ pos,
    float* __restrict__ partials)
{
    __shared__ float sums[4][64];   // per-wave partial row sums
    __shared__ float red[4];

    int tid = threadIdx.x;
    int n = blockIdx.x;
    int g = (n & 7) + 8 * (n >> 7);   // all 16 blocks of a graph share XCD (n%8 model)
    int stripe = (n >> 3) & 15;
    int w = tid >> 6, l = tid & 63;
    const unsigned short* z1g = z1n + (size_t)g * GSIZE * DIM;
    const unsigned short* z2g = z2n + (size_t)g * GSIZE * DIM;
    int rowBase = stripe * 64;

    // A fragments: 64 rows, 4 tiles x 2 K-halves. row = rowBase + rt*16 + (l&15)
    int ar = l & 15, ak = (l >> 4) * 8;
    frag_ab A[4][2];
    #pragma unroll
    for (int rt = 0; rt < 4; ++rt) {
        const unsigned short* p = z1g + (rowBase + rt * 16 + ar) * DIM + ak;
        A[rt][0] = *(const frag_ab*)(p);
        A[rt][1] = *(const frag_ab*)(p + 32);
    }

    float expacc[4][4] = {};   // static indexing only

    // Column stream: wave w covers virtual cols [w*512, w*512+512) of [z2 | z1].
    const unsigned short* sb =
        ((w < 2) ? z2g : z1g) + (((w & 1) * 512 + ar) * DIM + ak);

    const float K1 = 2.8853900817779268f;   // 2 * log2(e)   (inv_t=2 folded)
    const float K0 = -2.8853900817779268f;  // -2 * log2(e)  (fixed shift m=2)

    auto compute = [&](frag_ab b0, frag_ab b1) {
        f32x4 z = {0.f, 0.f, 0.f, 0.f};
        // phase 1: all MFMAs back-to-back
        f32x4 c0 = __builtin_amdgcn_mfma_f32_16x16x32_bf16(A[0][0], b0, z, 0, 0, 0);
        f32x4 c1 = __builtin_amdgcn_mfma_f32_16x16x32_bf16(A[1][0], b0, z, 0, 0, 0);
        f32x4 c2 = __builtin_amdgcn_mfma_f32_16x16x32_bf16(A[2][0], b0, z, 0, 0, 0);
        f32x4 c3 = __builtin_amdgcn_mfma_f32_16x16x32_bf16(A[3][0], b0, z, 0, 0, 0);
        c0 = __builtin_amdgcn_mfma_f32_16x16x32_bf16(A[0][1], b1, c0, 0, 0, 0);
        c1 = __builtin_amdgcn_mfma_f32_16x16x32_bf16(A[1][1], b1, c1, 0, 0, 0);
        c2 = __builtin_amdgcn_mfma_f32_16x16x32_bf16(A[2][1], b1, c2, 0, 0, 0);
        c3 = __builtin_amdgcn_mfma_f32_16x16x32_bf16(A[3][1], b1, c3, 0, 0, 0);
        // phase 2: exp/accumulate
        #pragma unroll
        for (int r = 0; r < 4; ++r) {
            expacc[0][r] += __builtin_amdgcn_exp2f(fmaf(c0[r], K1, K0));
            expacc[1][r] += __builtin_amdgcn_exp2f(fmaf(c1[r], K1, K0));
            expacc[2][r] += __builtin_amdgcn_exp2f(fmaf(c2[r], K1, K0));
            expacc[3][r] += __builtin_amdgcn_exp2f(fmaf(c3[r], K1, K0));
        }
    };

    const int T = 16 * DIM;   // one 16-col tile stride, in ushort units
    frag_ab p0a = *(const frag_ab*)(sb + 0 * T), p0b = *(const frag_ab*)(sb + 0 * T + 32);
    frag_ab p1a = *(const frag_ab*)(sb + 1 * T), p1b = *(const frag_ab*)(sb + 1 * T + 32);
    frag_ab p2a = *(const frag_ab*)(sb + 2 * T), p2b = *(const frag_ab*)(sb + 2 * T + 32);
    frag_ab p3a = *(const frag_ab*)(sb + 3 * T), p3b = *(const frag_ab*)(sb + 3 * T + 32);

    #pragma unroll 1
    for (int t = 0; t < 28; t += 4) {
        compute(p0a, p0b);
        p0a = *(const frag_ab*)(sb + 4 * T); p0b = *(const frag_ab*)(sb + 4 * T + 32);
        compute(p1a, p1b);
        p1a = *(const frag_ab*)(sb + 5 * T); p1b = *(const frag_ab*)(sb + 5 * T + 32);
        compute(p2a, p2b);
        p2a = *(const frag_ab*)(sb + 6 * T); p2b = *(const frag_ab*)(sb + 6 * T + 32);
        compute(p3a, p3b);
        p3a = *(const frag_ab*)(sb + 7 * T); p3b = *(const frag_ab*)(sb + 7 * T + 32);
        sb += 4 * T;
    }
    // epilogue: tiles 28..31, no reloads
    compute(p0a, p0b);
    compute(p1a, p1b);
    compute(p2a, p2b);
    compute(p3a, p3b);

    // Reduce C cols (low-4 lane bits); C/D layout: row = (l>>4)*4 + r, col = l&15.
    #pragma unroll
    for (int rt = 0; rt < 4; ++rt) {
        #pragma unroll
        for (int r = 0; r < 4; ++r) {
            float s = expacc[rt][r];
            s += __shfl_xor(s, 1); s += __shfl_xor(s, 2);
            s += __shfl_xor(s, 4); s += __shfl_xor(s, 8);
            if ((l & 15) == 0) sums[w][rt * 16 + (l >> 4) * 4 + r] = s;
        }
    }
    __syncthreads();

    float term = 0.f;
    if (tid < 64) {
        float S = sums[0][tid] + sums[1][tid] + sums[2][tid] + sums[3][tid];
        // shift m=2; sim11 diag contributes exp(0)=1, excluded in closed form
        term = 2.0f + __logf(S - 1.0f) - pos[g * GSIZE + rowBase + tid];
    }
    #pragma unroll
    for (int m = 1; m < 64; m <<= 1) term += __shfl_xor(term, m);
    if (l == 0) red[w] = term;   // waves 1..3 contribute 0
    __syncthreads();
    if (tid == 0) partials[n] = red[0] + red[1] + red[2] + red[3];
}

// Kernel 3: deterministic 1024 -> 1 reduce, mean over nodes.
__global__ __launch_bounds__(256) void final_reduce_k(
    const float* __restrict__ partials, float* __restrict__ out)
{
    int tid = threadIdx.x;
    float s = partials[tid] + partials[tid + 256] + partials[tid + 512] + partials[tid + 768];
    #pragma unroll
    for (int m = 1; m < 64; m <<= 1) s += __shfl_xor(s, m);
    __shared__ float red[4];
    if ((tid & 63) == 0) red[tid >> 6] = s;
    __syncthreads();
    if (tid == 0) out[0] = (red[0] + red[1] + red[2] + red[3]) * (1.0f / N_NODES);
}

extern "C" void kernel_launch(void* const* d_in, const int* in_sizes, int n_in,
                              void* d_out, int out_size, void* d_ws, size_t ws_size,
                              hipStream_t stream)
{
    const float* z1 = (const float*)d_in[0];
    const float* z2 = (const float*)d_in[1];
    char* ws = (char*)d_ws;
    unsigned short* z1n = (unsigned short*)ws;                       // 8 MB
    unsigned short* z2n = (unsigned short*)(ws + 8388608);           // 8 MB
    float* pos          = (float*)(ws + 16777216);                   // 256 KB
    float* partials     = (float*)(ws + 17039360);                   // 4 KB

    normalize_k<<<dim3(N_NODES / 16), dim3(256), 0, stream>>>(z1, z2, z1n, z2n, pos);
    grace_main_k<<<dim3(NUM_G * 16), dim3(256), 0, stream>>>(z1n, z2n, pos, partials);
    final_reduce_k<<<dim3(1), dim3(256), 0, stream>>>(partials, (float*)d_out);
}

// Round 8
// 53.890 us; speedup vs baseline: 1.6418x; 1.0929x over previous
//
#include <hip/hip_runtime.h>
#include <hip/hip_bf16.h>

#define N_NODES 65536
#define NUM_G   64
#define GSIZE   1024
#define DIM     64

using frag_ab = __attribute__((ext_vector_type(8))) short;   // 8 bf16 (4 VGPRs)
using f32x4   = __attribute__((ext_vector_type(4))) float;   // 4 fp32 accum

__device__ __forceinline__ unsigned short f2bf(float x) {
    union { float f; unsigned int u; } v; v.f = x;
    unsigned int r = v.u + 0x7FFFu + ((v.u >> 16) & 1u);   // RNE
    return (unsigned short)(r >> 16);
}

// Full-rate VALU exp2 (no trans pipe): floor + 5xfma Horner + ldexp.
// x in [-12, 0.1]; rel err ~2e-7.
__device__ __forceinline__ float exp2_poly(float x) {
    float xi = floorf(x);
    float t  = x - xi;
    float p  = fmaf(t, 0.00133335581f, 0.00961812963f);
    p = fmaf(t, p, 0.0555041086f);
    p = fmaf(t, p, 0.240226512f);
    p = fmaf(t, p, 0.693147182f);
    p = fmaf(t, p, 1.0f);
    return ldexpf(p, (int)xi);   // v_cvt_i32_f32 + v_ldexp_f32
}

// Kernel 1: fp32 row-normalize z1,z2 -> bf16 copies; pos = (z1n . z2n) * inv_t (fp32).
__global__ __launch_bounds__(256) void normalize_k(
    const float* __restrict__ z1, const float* __restrict__ z2,
    unsigned short* __restrict__ z1n, unsigned short* __restrict__ z2n,
    float* __restrict__ pos)
{
    int tid = threadIdx.x;
    int row = blockIdx.x * 16 + (tid >> 4);
    int l4  = tid & 15;
    float4 v1 = *((const float4*)(z1 + (size_t)row * DIM) + l4);
    float4 v2 = *((const float4*)(z2 + (size_t)row * DIM) + l4);
    float ss1 = v1.x*v1.x + v1.y*v1.y + v1.z*v1.z + v1.w*v1.w;
    float ss2 = v2.x*v2.x + v2.y*v2.y + v2.z*v2.z + v2.w*v2.w;
    float dt  = v1.x*v2.x + v1.y*v2.y + v1.z*v2.z + v1.w*v2.w;
    #pragma unroll
    for (int m = 1; m < 16; m <<= 1) {
        ss1 += __shfl_xor(ss1, m);
        ss2 += __shfl_xor(ss2, m);
        dt  += __shfl_xor(dt,  m);
    }
    float in1 = 1.0f / sqrtf(ss1);
    float in2 = 1.0f / sqrtf(ss2);
    ushort4 o1, o2;
    o1.x = f2bf(v1.x*in1); o1.y = f2bf(v1.y*in1); o1.z = f2bf(v1.z*in1); o1.w = f2bf(v1.w*in1);
    o2.x = f2bf(v2.x*in2); o2.y = f2bf(v2.y*in2); o2.z = f2bf(v2.z*in2); o2.w = f2bf(v2.w*in2);
    *((ushort4*)(z1n + (size_t)row * DIM) + l4) = o1;
    *((ushort4*)(z2n + (size_t)row * DIM) + l4) = o2;
    if (l4 == 0) pos[row] = dt * in1 * in2 * 2.0f;   // inv_t = 2
}

// Kernel 2: no LDS staging, no main-loop barriers; 1024 blocks = 64 graphs x 16
// stripes of 64 rows; B-stream straight from L2 (XCD-clustered), 2-deep prefetch.
// HYBRID EXP: rt 0,1 use native v_exp_f32 (trans pipe), rt 2,3 use VALU
// polynomial -- splits the 1.34e8 exps across two pipes (R7 analysis: trans
// is the structure-invariant ~27us wall; VALUBusy/MfmaUtil account for the rest).
__global__ __launch_bounds__(256, 4) void grace_main_k(
    const unsigned short* __restrict__ z1n,
    const unsigned short* __restrict__ z2n,
    const float* __restrict__ pos,
    float* __restrict__ partials)
{
    __shared__ float sums[4][64];   // per-wave partial row sums
    __shared__ float red[4];

    int tid = threadIdx.x;
    int n = blockIdx.x;
    int g = (n & 7) + 8 * (n >> 7);   // all 16 blocks of a graph share XCD (n%8 model)
    int stripe = (n >> 3) & 15;
    int w = tid >> 6, l = tid & 63;
    const unsigned short* z1g = z1n + (size_t)g * GSIZE * DIM;
    const unsigned short* z2g = z2n + (size_t)g * GSIZE * DIM;
    int rowBase = stripe * 64;

    // A fragments: 64 rows, 4 tiles x 2 K-halves. row = rowBase + rt*16 + (l&15)
    int ar = l & 15, ak = (l >> 4) * 8;
    frag_ab A[4][2];
    #pragma unroll
    for (int rt = 0; rt < 4; ++rt) {
        const unsigned short* p = z1g + (rowBase + rt * 16 + ar) * DIM + ak;
        A[rt][0] = *(const frag_ab*)(p);
        A[rt][1] = *(const frag_ab*)(p + 32);
    }

    float expacc[4][4] = {};   // static indexing only

    // Column stream: wave w covers virtual cols [w*512, w*512+512) of [z2 | z1].
    const unsigned short* sb =
        ((w < 2) ? z2g : z1g) + (((w & 1) * 512 + ar) * DIM + ak);

    const float K1 = 2.8853900817779268f;   // 2 * log2(e)   (inv_t=2 folded)
    const float K0 = -2.8853900817779268f;  // -2 * log2(e)  (fixed shift m=2)

    auto compute = [&](frag_ab b0, frag_ab b1) {
        f32x4 z = {0.f, 0.f, 0.f, 0.f};
        // phase 1: all MFMAs back-to-back
        f32x4 c0 = __builtin_amdgcn_mfma_f32_16x16x32_bf16(A[0][0], b0, z, 0, 0, 0);
        f32x4 c1 = __builtin_amdgcn_mfma_f32_16x16x32_bf16(A[1][0], b0, z, 0, 0, 0);
        f32x4 c2 = __builtin_amdgcn_mfma_f32_16x16x32_bf16(A[2][0], b0, z, 0, 0, 0);
        f32x4 c3 = __builtin_amdgcn_mfma_f32_16x16x32_bf16(A[3][0], b0, z, 0, 0, 0);
        c0 = __builtin_amdgcn_mfma_f32_16x16x32_bf16(A[0][1], b1, c0, 0, 0, 0);
        c1 = __builtin_amdgcn_mfma_f32_16x16x32_bf16(A[1][1], b1, c1, 0, 0, 0);
        c2 = __builtin_amdgcn_mfma_f32_16x16x32_bf16(A[2][1], b1, c2, 0, 0, 0);
        c3 = __builtin_amdgcn_mfma_f32_16x16x32_bf16(A[3][1], b1, c3, 0, 0, 0);
        // phase 2: hybrid exp. Issue trans ops first (run in background),
        // then poly on the main VALU, then the trans-dependent adds.
        #pragma unroll
        for (int r = 0; r < 4; ++r) {
            expacc[0][r] += __builtin_amdgcn_exp2f(fmaf(c0[r], K1, K0));  // trans
            expacc[1][r] += __builtin_amdgcn_exp2f(fmaf(c1[r], K1, K0));  // trans
            expacc[2][r] += exp2_poly(fmaf(c2[r], K1, K0));               // VALU
            expacc[3][r] += exp2_poly(fmaf(c3[r], K1, K0));               // VALU
        }
    };

    frag_ab bA0 = *(const frag_ab*)(sb);
    frag_ab bA1 = *(const frag_ab*)(sb + 32);

    #pragma unroll 1
    for (int t = 0; t < 32; t += 2) {
        frag_ab bB0 = *(const frag_ab*)(sb + 16 * DIM);        // tile t+1
        frag_ab bB1 = *(const frag_ab*)(sb + 16 * DIM + 32);
        compute(bA0, bA1);                                     // tile t
        if (t < 30) {
            bA0 = *(const frag_ab*)(sb + 32 * DIM);            // tile t+2
            bA1 = *(const frag_ab*)(sb + 32 * DIM + 32);
        }
        compute(bB0, bB1);                                     // tile t+1
        sb += 32 * DIM;
    }

    // Reduce C cols (low-4 lane bits); C/D layout: row = (l>>4)*4 + r, col = l&15.
    #pragma unroll
    for (int rt = 0; rt < 4; ++rt) {
        #pragma unroll
        for (int r = 0; r < 4; ++r) {
            float s = expacc[rt][r];
            s += __shfl_xor(s, 1); s += __shfl_xor(s, 2);
            s += __shfl_xor(s, 4); s += __shfl_xor(s, 8);
            if ((l & 15) == 0) sums[w][rt * 16 + (l >> 4) * 4 + r] = s;
        }
    }
    __syncthreads();

    float term = 0.f;
    if (tid < 64) {
        float S = sums[0][tid] + sums[1][tid] + sums[2][tid] + sums[3][tid];
        // shift m=2; sim11 diag contributes exp(0)=1, excluded in closed form
        term = 2.0f + __logf(S - 1.0f) - pos[g * GSIZE + rowBase + tid];
    }
    #pragma unroll
    for (int m = 1; m < 64; m <<= 1) term += __shfl_xor(term, m);
    if (l == 0) red[w] = term;   // waves 1..3 contribute 0
    __syncthreads();
    if (tid == 0) partials[n] = red[0] + red[1] + red[2] + red[3];
}

// Kernel 3: deterministic 1024 -> 1 reduce, mean over nodes.
__global__ __launch_bounds__(256) void final_reduce_k(
    const float* __restrict__ partials, float* __restrict__ out)
{
    int tid = threadIdx.x;
    float s = partials[tid] + partials[tid + 256] + partials[tid + 512] + partials[tid + 768];
    #pragma unroll
    for (int m = 1; m < 64; m <<= 1) s += __shfl_xor(s, m);
    __shared__ float red[4];
    if ((tid & 63) == 0) red[tid >> 6] = s;
    __syncthreads();
    if (tid == 0) out[0] = (red[0] + red[1] + red[2] + red[3]) * (1.0f / N_NODES);
}

extern "C" void kernel_launch(void* const* d_in, const int* in_sizes, int n_in,
                              void* d_out, int out_size, void* d_ws, size_t ws_size,
                              hipStream_t stream)
{
    const float* z1 = (const float*)d_in[0];
    const float* z2 = (const float*)d_in[1];
    char* ws = (char*)d_ws;
    unsigned short* z1n = (unsigned short*)ws;                       // 8 MB
    unsigned short* z2n = (unsigned short*)(ws + 8388608);           // 8 MB
    float* pos          = (float*)(ws + 16777216);                   // 256 KB
    float* partials     = (float*)(ws + 17039360);                   // 4 KB

    normalize_k<<<dim3(N_NODES / 16), dim3(256), 0, stream>>>(z1, z2, z1n, z2n, pos);
    grace_main_k<<<dim3(NUM_G * 16), dim3(256), 0, stream>>>(z1n, z2n, pos, partials);
    final_reduce_k<<<dim3(1), dim3(256), 0, stream>>>(partials, (float*)d_out);
}